// Round 10
// baseline (434.413 us; speedup 1.0000x reference)
//
#include <hip/hip_runtime.h>
#include <hip/hip_bf16.h>

// GlobalFilter: y = irfft2(rfft2(x, ortho) * W, ortho) over axes (1,2)
// == per-channel 14x14 circular conv with real kernel k_c = ifft2(M_c):
//   k_c[p,q] = (1/196) * sum_{u<14,v<8} c_v*(Wr*cos(th) - Wi*sin(th)),
//   th = 2*pi*(u*p+v*q)/14, c_v = 1 for v in {0,7} else 2.
//
// v10: R9 killed spill (amdgpu_waves_per_eu(1,4)) but 1-wave workgroups hit
// the CP dispatch-rate ceiling (10752 wg @ ~13ns/wg, occupancy 3.4 waves/CU).
// Now: 4 independent waves per 256-thr workgroup (no LDS/barriers), one
// OUTPUT ROW per wave, float2 lanes pair input rows (2i,2i+1) against k-rows
// (d0,d0-1); horizontal add in epilogue. Pure f32 (packed f16 measured
// half-rate in R9 -> no benefit). A/B: batches 0..63 scalar fmaf,
// 64..127 float2 fma -> v_pk_fma_f32 rate measurement.

typedef float f2 __attribute__((ext_vector_type(2)));

#define CC 768

// ---------------- Kernel A: plain spatial kernels k[196][768] f32 ----------------
// grid (12 cgroups, 14 p), 896 threads = 14 q x 64 ch.
__global__ __launch_bounds__(896) void gf_build_k(const float* __restrict__ wg,
                                                  float* __restrict__ kbuf) {
    __shared__ float ws[112 * 128];        // [uv][cl][ri], pre-scaled by cv/196
    __shared__ float ct[14], st[14];
    int t = threadIdx.x;
    int c0 = blockIdx.x * 64;
    int p  = blockIdx.y;
    if (t < 14) {
        float ang = 6.283185307179586f * (float)t / 14.0f;
        ct[t] = cosf(ang);
        st[t] = sinf(ang);
    }
    #pragma unroll
    for (int j = 0; j < 16; ++j) {
        int f = t + j * 896;               // 0..14335
        int uv = f >> 7;
        int v = uv & 7;
        float scale = (v == 0 || v == 7) ? (1.0f / 196.0f) : (2.0f / 196.0f);
        ws[f] = wg[(size_t)uv * 1536 + (size_t)c0 * 2 + (f & 127)] * scale;
    }
    __syncthreads();

    int q = t >> 6, cl = t & 63;
    float a = 0.f;
    int up = 0;                            // (u*p) % 14
    #pragma unroll
    for (int u = 0; u < 14; ++u) {
        int r = up;                        // (u*p + v*q) % 14
        #pragma unroll
        for (int v = 0; v < 8; ++v) {
            float wr = ws[(u * 8 + v) * 128 + cl * 2];
            float wi = ws[(u * 8 + v) * 128 + cl * 2 + 1];
            a += wr * ct[r] - wi * st[r];
            r += q; if (r >= 14) r -= 14;
        }
        up += p; if (up >= 14) up -= 14;
    }
    kbuf[(size_t)(p * 14 + q) * CC + c0 + cl] = a;
}

// ---------------- Kernel B: depthwise circular conv, row-paired float2 ----------------
// grid 2688 x 256 thr = 10752 waves = 12 cg x 64 b x 14 h per dispatch.
// wave -> one output row h of one (batch, 64ch group).
// acc[w].x += k[d0][q]   * x[2i][w-q]     (d0 = (h-2i) mod 14)
// acc[w].y += k[d0-1][q] * x[2i+1][w-q]
template<bool USE_PK>
__global__ __launch_bounds__(256)
__attribute__((amdgpu_waves_per_eu(1, 4)))
void gf_conv10(const float* __restrict__ x, const float* __restrict__ kbuf,
               float* __restrict__ y, int b_base) {
    int bid = blockIdx.x;                  // 0..2687
    int swz = (bid & 7) * 336 + (bid >> 3);        // XCD chunking (2688 = 8*336)
    int wid = swz * 4 + (threadIdx.x >> 6);        // 0..10751
    int cg  = wid / 896;                   // 0..11  (896 = 64 b * 14 h)
    int rem = wid - cg * 896;
    int bb  = rem / 14;
    int b   = b_base + bb;                 // batch
    int h   = rem - bb * 14;               // output row 0..13
    int cl  = threadIdx.x & 63;            // lane = channel

    const float* xb = x + (size_t)b * 196 * CC + cg * 64 + cl;
    const float* kb = kbuf + cg * 64 + cl;
    float* yb = y + ((size_t)b * 196 + h * 14) * CC + cg * 64 + cl;

    f2 acc[14];
    #pragma unroll
    for (int w = 0; w < 14; ++w) acc[w] = (f2)(0.f);

    f2 xr[2][14];                          // row-pair double buffer
    #pragma unroll
    for (int w = 0; w < 14; ++w) {         // prologue: rows 0,1
        xr[0][w].x = xb[(0 * 14 + w) * CC];
        xr[0][w].y = xb[(1 * 14 + w) * CC];
    }

    int d0 = h;                            // (h - 2i) mod 14
    #pragma unroll
    for (int i = 0; i < 7; ++i) {
        const int xc = i & 1, xn = xc ^ 1; // static after unroll

        if (i < 6) {                       // prefetch rows 2i+2, 2i+3
            #pragma unroll
            for (int w = 0; w < 14; ++w) {
                xr[xn][w].x = xb[((2 * i + 2) * 14 + w) * CC];
                xr[xn][w].y = xb[((2 * i + 3) * 14 + w) * CC];
            }
        }
        int d1 = (d0 == 0) ? 13 : d0 - 1;

        #pragma unroll
        for (int half = 0; half < 2; ++half) {   // q split -> only 7 f2 of k live
            f2 kp[7];
            #pragma unroll
            for (int qq = 0; qq < 7; ++qq) {
                int q = half * 7 + qq;
                kp[qq].x = kb[(d0 * 14 + q) * CC];
                kp[qq].y = kb[(d1 * 14 + q) * CC];
            }
            #pragma unroll
            for (int qq = 0; qq < 7; ++qq) {
                int q = half * 7 + qq;     // compile-time
                #pragma unroll
                for (int w = 0; w < 14; ++w) {
                    int src = w - q; if (src < 0) src += 14;
                    if constexpr (USE_PK) {
                        acc[w] = kp[qq] * xr[xc][src] + acc[w];   // v_pk_fma_f32
                    } else {
                        acc[w].x = fmaf(kp[qq].x, xr[xc][src].x, acc[w].x);
                        acc[w].y = fmaf(kp[qq].y, xr[xc][src].y, acc[w].y);
                    }
                }
            }
        }
        d0 = (d0 >= 2) ? d0 - 2 : d0 + 12;
        // fence: no cross-step hoisting (register-pressure blowup -> spill)
        __builtin_amdgcn_sched_barrier(0);
    }

    #pragma unroll
    for (int w = 0; w < 14; ++w) yb[w * CC] = acc[w].x + acc[w].y;
}

extern "C" void kernel_launch(void* const* d_in, const int* in_sizes, int n_in,
                              void* d_out, int out_size, void* d_ws, size_t ws_size,
                              hipStream_t stream) {
    const float* x = (const float*)d_in[0];
    const float* w = (const float*)d_in[1];
    float* y = (float*)d_out;
    float* kbuf = (float*)d_ws;            // 196*768*4 = 602,112 B

    gf_build_k<<<dim3(12, 14), dim3(896), 0, stream>>>(w, kbuf);

    gf_conv10<false><<<dim3(2688), dim3(256), 0, stream>>>(x, kbuf, y, 0);   // scalar fmaf
    gf_conv10<true ><<<dim3(2688), dim3(256), 0, stream>>>(x, kbuf, y, 64);  // v_pk_fma_f32
}